// Round 8
// baseline (154.490 us; speedup 1.0000x reference)
//
#include <hip/hip_runtime.h>

// Fully-fused PINN-LISTA, transposed-MFMA + prep prefold + ILP-2 tiles.
// One 64-thread wave per block owns TWO independent 16-sample tiles
// (32 samples): 1024 blocks = exactly 1 wave/SIMD. Zero barriers and zero
// LDS traffic in the scan loop; each tile's dependency stalls are filled
// by the other tile's independent instructions. Weights shared.
// R8 fix: ISTA is Jacobi -- compute ALL z accumulators from the OLD x
// fragments, THEN threshold+repack (R7 overwrote xf mid-loop).

#define NB 32768
#define WIN 100
#define HH 64
#define AA 64
#define KITER 8
#define NAPPC 4
#define DTC 0.1f
#define LNEPS 1e-5f
#define K2E 2.8853900817779268f  // 2*log2(e)

// d_ws byte offsets
#define WS_WREC 0        // f16 [4][4][64][4]   = 8192 B   ([mt*4+kchunk][lane][4])
#define WS_WE   8192     // f16 [8][64][112]    = 114688 B (K padded 100->112, zeros)
#define WS_WR   122880   // f16 [8][64][64]     = 65536 B
#define WS_WC   188416   // f32 [64]
#define WS_BC   188672   // f32 [64]
#define WS_DEC  188928   // f32 [64]
#define WS_LAM  189184   // f32 [8][64] -> ends 191232

typedef _Float16 f16x4 __attribute__((ext_vector_type(4)));
typedef __fp16 fp16x2 __attribute__((ext_vector_type(2)));
typedef float f32x4 __attribute__((ext_vector_type(4)));

union H4 { f16x4 v; fp16x2 h[2]; };

__device__ __forceinline__ float exp2_fast(float x) { return __builtin_amdgcn_exp2f(x); }
__device__ __forceinline__ float rcp_fast(float x) { return __builtin_amdgcn_rcpf(x); }
__device__ __forceinline__ float rsq_fast(float x) { return __builtin_amdgcn_rsqf(x); }
__device__ __forceinline__ float log2_fast(float x) { return __builtin_amdgcn_logf(x); }
__device__ __forceinline__ float med3(float x, float lo, float hi) {
  return __builtin_amdgcn_fmed3f(x, lo, hi);
}
__device__ __forceinline__ float softplus_fast(float x) {
  float ax = fabsf(x);
  float e = exp2_fast(-ax * 1.4426950408889634f);
  return fmaxf(x, 0.0f) + log2_fast(1.0f + e) * 0.6931471805599453f;
}
__device__ __forceinline__ f16x4 pack4(float a, float b, float c2, float d) {
  H4 t;
  t.h[0] = __builtin_amdgcn_cvt_pkrtz(a, b);
  t.h[1] = __builtin_amdgcn_cvt_pkrtz(c2, d);
  return t.v;
}

// ======================= prep kernel =======================
__global__ __launch_bounds__(256) void pinn_prep(
    const float* __restrict__ W_rec, const float* __restrict__ w_in,
    const float* __restrict__ b_in, const float* __restrict__ tau,
    const float* __restrict__ thr, const float* __restrict__ We,
    const float* __restrict__ Wr, char* __restrict__ ws) {
  _Float16* wrec16 = (_Float16*)(ws + WS_WREC);
  _Float16* we16 = (_Float16*)(ws + WS_WE);
  _Float16* wr16 = (_Float16*)(ws + WS_WR);
  float* wc = (float*)(ws + WS_WC);
  float* bc = (float*)(ws + WS_BC);
  float* dec = (float*)(ws + WS_DEC);
  float* lam = (float*)(ws + WS_LAM);
  const int tid = threadIdx.x, bid = blockIdx.x;
  if (bid == 0) {
    __shared__ float rm[64];
    if (tid < 64) {
      float s = 0.f;
      for (int m = 0; m < 64; ++m) s += W_rec[tid * 64 + m];
      rm[tid] = s * (1.f / 64.f);
    }
    __syncthreads();
    for (int idx = tid; idx < 4096; idx += 256) {
      const int j = idx & 3, l = (idx >> 2) & 63, kt = (idx >> 8) & 3, mt = idx >> 10;
      const int k_in = kt * 16 + ((l >> 4) << 2) + j, m = mt * 16 + (l & 15);
      wrec16[idx] = (_Float16)(W_rec[k_in * 64 + m] - rm[k_in]);
    }
    if (tid < 64) {
      float sw = 0.f, sb = 0.f;
      for (int i = 0; i < 64; ++i) { sw += w_in[i]; sb += b_in[i]; }
      wc[tid] = w_in[tid] - sw * (1.f / 64.f);
      bc[tid] = b_in[tid] - sb * (1.f / 64.f);
      dec[tid] = 1.f - DTC / softplus_fast(tau[tid]);
    }
    for (int i = tid; i < 512; i += 256) lam[i] = softplus_fast(thr[i]);
  } else {
    const int stride = (gridDim.x - 1) * 256;
    for (int i = (bid - 1) * 256 + tid; i < 57344 + 32768; i += stride) {
      if (i < 57344) {
        const int row = i / 112, t = i - row * 112;
        we16[i] = (t < WIN) ? (_Float16)We[row * WIN + t] : (_Float16)0.f;
      } else {
        const int j = i - 57344;
        wr16[j] = (_Float16)Wr[j];
      }
    }
  }
}

// ======================= main kernel =======================
__global__ __launch_bounds__(64, 1) void pinn_fused(
    const float* __restrict__ y, const float* __restrict__ ln_w,
    const float* __restrict__ ln_b, const float* __restrict__ Wx0,
    const float* __restrict__ bx0, const float* __restrict__ be,
    const float* __restrict__ head_W, const float* __restrict__ head_b,
    const char* __restrict__ ws, float* __restrict__ out) {
  __shared__ float ybuf[32][101];

  const _Float16* wrec16 = (const _Float16*)(ws + WS_WREC);
  const _Float16* we16 = (const _Float16*)(ws + WS_WE);
  const _Float16* wr16 = (const _Float16*)(ws + WS_WR);
  const float* wcp = (const float*)(ws + WS_WC);
  const float* bcp = (const float*)(ws + WS_BC);
  const float* decp = (const float*)(ws + WS_DEC);
  const float* lamp = (const float*)(ws + WS_LAM);

  const int l = threadIdx.x;
  const int c = l & 15;  // sample-in-tile (C col / B col / A row)
  const int g = l >> 4;  // lane group
  const int s0 = blockIdx.x * 32;  // tile A: s0..s0+15, tile B: s0+16..s0+31

  // ---- stage y (32 samples) ----
  for (int i = l; i < 32 * WIN; i += 64) {
    const int s = i / WIN;
    ybuf[s][i - s * WIN] = y[s0 * WIN + i];
  }

  // ---- per-H constants (shared by both tiles): e = mt*4+r -> H = mt*16+4g+r ----
  float wc_r[16], bc_r[16], lnwK[16], lnbK[16], dec_r[16];
#pragma unroll
  for (int mt = 0; mt < 4; ++mt) {
    const int hb4 = mt * 16 + g * 4;
    const float4 wi = *(const float4*)&wcp[hb4];
    const float4 bi = *(const float4*)&bcp[hb4];
    const float4 lw = *(const float4*)&ln_w[hb4];
    const float4 lb = *(const float4*)&ln_b[hb4];
    const float4 dc = *(const float4*)&decp[hb4];
#pragma unroll
    for (int r = 0; r < 4; ++r) {
      wc_r[mt * 4 + r] = (&wi.x)[r];
      bc_r[mt * 4 + r] = (&bi.x)[r];
      lnwK[mt * 4 + r] = (&lw.x)[r] * K2E;
      lnbK[mt * 4 + r] = (&lb.x)[r] * K2E;
      dec_r[mt * 4 + r] = (&dc.x)[r];
    }
  }

  // ---- centered W' A-fragments (shared) ----
  f16x4 wrec[4][4];
#pragma unroll
  for (int mt = 0; mt < 4; ++mt)
#pragma unroll
    for (int kt = 0; kt < 4; ++kt)
      wrec[mt][kt] = *(const f16x4*)&wrec16[((mt * 4 + kt) * 64 + l) * 4];

  __syncthreads();  // ybuf ready

  float hsA[16] = {}, hsB[16] = {};
  f16x4 hbA[4] = {}, hbB[4] = {};
  const float inv64 = 1.0f / 64.0f;

  // ================= Phase 1: 100-step scan (no barriers) =================
  float xtA = ybuf[c][0], xtB = ybuf[c + 16][0];
  for (int t = 0; t < WIN; ++t) {
    const float xtnA = ybuf[c][t + 1];       // col 100 in-bounds, unused at t=99
    const float xtnB = ybuf[c + 16][t + 1];
    f32x4 accA[4], accB[4];
#pragma unroll
    for (int mt = 0; mt < 4; ++mt) {
      f32x4 a, b;
#pragma unroll
      for (int r = 0; r < 4; ++r) {
        a[r] = fmaf(xtA, wc_r[mt * 4 + r], bc_r[mt * 4 + r]);
        b[r] = fmaf(xtB, wc_r[mt * 4 + r], bc_r[mt * 4 + r]);
      }
#pragma unroll
      for (int kt = 0; kt < 4; ++kt) {
        a = __builtin_amdgcn_mfma_f32_16x16x16f16(wrec[mt][kt], hbA[kt], a, 0, 0, 0);
        b = __builtin_amdgcn_mfma_f32_16x16x16f16(wrec[mt][kt], hbB[kt], b, 0, 0, 0);
      }
      accA[mt] = a;
      accB[mt] = b;
    }
    // variance-only LN reduce per tile (d centered by construction)
    float qA = 0.f, qB = 0.f;
#pragma unroll
    for (int mt = 0; mt < 4; ++mt)
#pragma unroll
      for (int r = 0; r < 4; ++r) {
        qA = fmaf(accA[mt][r], accA[mt][r], qA);
        qB = fmaf(accB[mt][r], accB[mt][r], qB);
      }
    qA += __shfl_xor(qA, 16);
    qB += __shfl_xor(qB, 16);
    qA += __shfl_xor(qA, 32);
    qB += __shfl_xor(qB, 32);
    const float rstdA = rsq_fast(fmaf(qA, inv64, LNEPS));
    const float rstdB = rsq_fast(fmaf(qB, inv64, LNEPS));
#pragma unroll
    for (int mt = 0; mt < 4; ++mt) {
      float hnA[4], hnB[4];
#pragma unroll
      for (int r = 0; r < 4; ++r) {
        const int e = mt * 4 + r;
        const float uA = fmaf(accA[mt][r] * rstdA, lnwK[e], lnbK[e]);  // 2u*log2e
        const float uB = fmaf(accB[mt][r] * rstdB, lnwK[e], lnbK[e]);
        const float rA = rcp_fast(exp2_fast(uA) + 1.f);
        const float rB = rcp_fast(exp2_fast(uB) + 1.f);
        // DTC*tanh = fma(-0.2, rr, 0.1)
        hnA[r] = med3(fmaf(hsA[e], dec_r[e], fmaf(-0.2f, rA, 0.1f)), -10.f, 10.f);
        hnB[r] = med3(fmaf(hsB[e], dec_r[e], fmaf(-0.2f, rB, 0.1f)), -10.f, 10.f);
        hsA[e] = hnA[r];
        hsB[e] = hnB[r];
      }
      hbA[mt] = pack4(hnA[0], hnA[1], hnA[2], hnA[3]);
      hbB[mt] = pack4(hnB[0], hnB[1], hnB[2], hnB[3]);
    }
    xtA = xtnA;
    xtB = xtnB;
  }

  // ================= Phase 2: x^T = Wx0 @ h^T + bx0 (shared weight loads) =================
  float xsA[16], xsB[16];
  f16x4 xfA[4], xfB[4];
#pragma unroll
  for (int mt = 0; mt < 4; ++mt) {
    const float4 b4 = *(const float4*)&bx0[mt * 16 + 4 * g];
    f32x4 a = {b4.x, b4.y, b4.z, b4.w};
    f32x4 b = a;
#pragma unroll
    for (int kt = 0; kt < 4; ++kt) {
      const float4 wv = *(const float4*)&Wx0[(mt * 16 + c) * HH + kt * 16 + 4 * g];
      const f16x4 wf = pack4(wv.x, wv.y, wv.z, wv.w);
      a = __builtin_amdgcn_mfma_f32_16x16x16f16(wf, hbA[kt], a, 0, 0, 0);
      b = __builtin_amdgcn_mfma_f32_16x16x16f16(wf, hbB[kt], b, 0, 0, 0);
    }
#pragma unroll
    for (int r = 0; r < 4; ++r) {
      xsA[mt * 4 + r] = a[r];
      xsB[mt * 4 + r] = b[r];
    }
    xfA[mt] = pack4(a[0], a[1], a[2], a[3]);
    xfB[mt] = pack4(b[0], b[1], b[2], b[3]);
  }

  // ---- y^T B-fragments per tile (t >= 100 zero; We padded in ws) ----
  f16x4 yfA[7], yfB[7];
#pragma unroll
  for (int kt = 0; kt < 7; ++kt) {
    const int t0 = kt * 16 + 4 * g;
    if (t0 + 3 < WIN) {
      yfA[kt] = pack4(ybuf[c][t0], ybuf[c][t0 + 1], ybuf[c][t0 + 2], ybuf[c][t0 + 3]);
      yfB[kt] = pack4(ybuf[c + 16][t0], ybuf[c + 16][t0 + 1], ybuf[c + 16][t0 + 2], ybuf[c + 16][t0 + 3]);
    } else {
      yfA[kt] = pack4(0.f, 0.f, 0.f, 0.f);
      yfB[kt] = pack4(0.f, 0.f, 0.f, 0.f);
    }
  }

  // ================= Phase 3: ISTA (Jacobi: all z from OLD x, then threshold) =================
  for (int k = 0; k < KITER; ++k) {
    f32x4 zA[4], zB[4];
#pragma unroll
    for (int mt = 0; mt < 4; ++mt) {
      const float4 be4 = *(const float4*)&be[k * AA + mt * 16 + 4 * g];
      f32x4 a = {be4.x, be4.y, be4.z, be4.w};
      f32x4 b = a;
      const int rowe = (k * AA + mt * 16 + c) * 112;
#pragma unroll
      for (int kt = 0; kt < 7; ++kt) {
        const f16x4 wf = *(const f16x4*)&we16[rowe + kt * 16 + 4 * g];
        a = __builtin_amdgcn_mfma_f32_16x16x16f16(wf, yfA[kt], a, 0, 0, 0);
        b = __builtin_amdgcn_mfma_f32_16x16x16f16(wf, yfB[kt], b, 0, 0, 0);
      }
      const int rowr = (k * AA + mt * 16 + c) * AA;
#pragma unroll
      for (int kt = 0; kt < 4; ++kt) {
        const f16x4 wf = *(const f16x4*)&wr16[rowr + kt * 16 + 4 * g];
        a = __builtin_amdgcn_mfma_f32_16x16x16f16(wf, xfA[kt], a, 0, 0, 0);
        b = __builtin_amdgcn_mfma_f32_16x16x16f16(wf, xfB[kt], b, 0, 0, 0);
      }
      zA[mt] = a;
      zB[mt] = b;
    }
#pragma unroll
    for (int mt = 0; mt < 4; ++mt) {
      const float4 lm4 = *(const float4*)&lamp[k * AA + mt * 16 + 4 * g];
      float xvA[4], xvB[4];
#pragma unroll
      for (int r = 0; r < 4; ++r) {
        const float lam = (&lm4.x)[r];
        const float a = zA[mt][r], b = zB[mt][r];
        xvA[r] = copysignf(fmaxf(fabsf(a) - lam, 0.0f), a);
        xvB[r] = copysignf(fmaxf(fabsf(b) - lam, 0.0f), b);
        xsA[mt * 4 + r] = xvA[r];
        xsB[mt * 4 + r] = xvB[r];
      }
      xfA[mt] = pack4(xvA[0], xvA[1], xvA[2], xvA[3]);
      xfB[mt] = pack4(xvB[0], xvB[1], xvB[2], xvB[3]);
    }
  }

  // ================= Phase 4: outputs =================
  float* __restrict__ outp = out;               // power (B, 4)
  float* __restrict__ outx = out + NB * NAPPC;  // x (B, 64)
#pragma unroll
  for (int mt = 0; mt < 4; ++mt) {
    float4 vA, vB;
#pragma unroll
    for (int r = 0; r < 4; ++r) {
      (&vA.x)[r] = xsA[mt * 4 + r];
      (&vB.x)[r] = xsB[mt * 4 + r];
    }
    *(float4*)&outx[(s0 + c) * AA + mt * 16 + 4 * g] = vA;
    *(float4*)&outx[(s0 + 16 + c) * AA + mt * 16 + 4 * g] = vB;
  }

  // head: per-appliance dot over 64 elems (shared head_W loads), butterfly over g
  float PA[4], PB[4];
#pragma unroll
  for (int p = 0; p < NAPPC; ++p) {
    float acc = 0.f, acc2 = 0.f;
#pragma unroll
    for (int mt = 0; mt < 4; ++mt) {
      const float4 hw = *(const float4*)&head_W[p * AA + mt * 16 + 4 * g];
#pragma unroll
      for (int r = 0; r < 4; ++r) {
        acc = fmaf(xsA[mt * 4 + r], (&hw.x)[r], acc);
        acc2 = fmaf(xsB[mt * 4 + r], (&hw.x)[r], acc2);
      }
    }
    acc += __shfl_xor(acc, 16);
    acc2 += __shfl_xor(acc2, 16);
    acc += __shfl_xor(acc, 32);
    acc2 += __shfl_xor(acc2, 32);
    PA[p] = acc + head_b[p];
    PB[p] = acc2 + head_b[p];
  }
  if (g == 0) {
    float4 pv;
#pragma unroll
    for (int p = 0; p < NAPPC; ++p) (&pv.x)[p] = PA[p];
    *(float4*)&outp[(s0 + c) * NAPPC] = pv;
  }
  if (g == 1) {
    float4 pv;
#pragma unroll
    for (int p = 0; p < NAPPC; ++p) (&pv.x)[p] = PB[p];
    *(float4*)&outp[(s0 + 16 + c) * NAPPC] = pv;
  }
}

extern "C" void kernel_launch(void* const* d_in, const int* in_sizes, int n_in,
                              void* d_out, int out_size, void* d_ws, size_t ws_size,
                              hipStream_t stream) {
  const float* y         = (const float*)d_in[0];
  const float* w_in      = (const float*)d_in[1];
  const float* b_in      = (const float*)d_in[2];
  const float* tau_param = (const float*)d_in[3];
  const float* W_rec     = (const float*)d_in[4];
  const float* ln_w      = (const float*)d_in[5];
  const float* ln_b      = (const float*)d_in[6];
  const float* Wx0       = (const float*)d_in[7];
  const float* bx0       = (const float*)d_in[8];
  const float* We        = (const float*)d_in[9];
  const float* be        = (const float*)d_in[10];
  const float* Wr        = (const float*)d_in[11];
  const float* thr       = (const float*)d_in[12];
  const float* head_W    = (const float*)d_in[13];
  const float* head_b    = (const float*)d_in[14];

  pinn_prep<<<dim3(90), dim3(256), 0, stream>>>(
      W_rec, w_in, b_in, tau_param, thr, We, Wr, (char*)d_ws);
  pinn_fused<<<dim3(NB / 32), dim3(64), 0, stream>>>(
      y, ln_w, ln_b, Wx0, bx0, be, head_W, head_b, (const char*)d_ws,
      (float*)d_out);
}

// Round 9
// 128.113 us; speedup vs baseline: 1.2059x; 1.2059x over previous
//
#include <hip/hip_runtime.h>

// Fully-fused PINN-LISTA, transposed-MFMA + prep prefold + packed-f16 scan.
// R9: back to R4 structure (1 wave = 16 samples, 2048 blocks = 2 waves/SIMD,
// HW-guaranteed interleave) but with the scan elementwise phase in packed
// f16 (v_pk_*), h state stored AS the f16 B-fragments (no pack step), per-H
// constants in f16x2 (half the registers -> everything stays resident, no
// per-iteration L2 reloads), variance via v_dot2_f32_f16, and tanh via a
// clamped [3/2] Pade rational (1 v_rcp_f16 instead of exp2+rcp per elem).

#define NB 32768
#define WIN 100
#define HH 64
#define AA 64
#define KITER 8
#define NAPPC 4
#define LNEPS 1e-5f
#define DTC 0.1f

// d_ws byte offsets
#define WS_WREC 0        // f16 [4][4][64][4]   = 8192 B   ([mt*4+kchunk][lane][4])
#define WS_WE   8192     // f16 [8][64][112]    = 114688 B (K padded 100->112, zeros)
#define WS_WR   122880   // f16 [8][64][64]     = 65536 B
#define WS_WC   188416   // f32 [64]
#define WS_BC   188672   // f32 [64]
#define WS_DEC  188928   // f32 [64]
#define WS_LAM  189184   // f32 [8][64] -> ends 191232

typedef _Float16 f16x4 __attribute__((ext_vector_type(4)));
typedef _Float16 f16x2v __attribute__((ext_vector_type(2)));
typedef __fp16 fp16x2 __attribute__((ext_vector_type(2)));
typedef float f32x4 __attribute__((ext_vector_type(4)));

union H4 { f16x4 v; fp16x2 h[2]; };
union HS { f16x2v p[2]; f16x4 v; };
union FD { f16x2v h; fp16x2 u; };

__device__ __forceinline__ float exp2_fast(float x) { return __builtin_amdgcn_exp2f(x); }
__device__ __forceinline__ float rsq_fast(float x) { return __builtin_amdgcn_rsqf(x); }
__device__ __forceinline__ float log2_fast(float x) { return __builtin_amdgcn_logf(x); }
__device__ __forceinline__ float softplus_fast(float x) {
  float ax = fabsf(x);
  float e = exp2_fast(-ax * 1.4426950408889634f);
  return fmaxf(x, 0.0f) + log2_fast(1.0f + e) * 0.6931471805599453f;
}
__device__ __forceinline__ f16x4 pack4(float a, float b, float c2, float d) {
  H4 t;
  t.h[0] = __builtin_amdgcn_cvt_pkrtz(a, b);
  t.h[1] = __builtin_amdgcn_cvt_pkrtz(c2, d);
  return t.v;
}
__device__ __forceinline__ f16x2v pk2(float a, float b) {
  FD t;
  t.u = __builtin_amdgcn_cvt_pkrtz(a, b);
  return t.h;
}
__device__ __forceinline__ float fdot2f(f16x2v a, f16x2v b, float c) {
  FD A, B;
  A.h = a;
  B.h = b;
  return __builtin_amdgcn_fdot2(A.u, B.u, c, false);
}
__device__ __forceinline__ f16x2v rcp2(f16x2v d) {
  f16x2v r;
  r[0] = __builtin_amdgcn_rcph(d[0]);
  r[1] = __builtin_amdgcn_rcph(d[1]);
  return r;
}

// ======================= prep kernel =======================
__global__ __launch_bounds__(256) void pinn_prep(
    const float* __restrict__ W_rec, const float* __restrict__ w_in,
    const float* __restrict__ b_in, const float* __restrict__ tau,
    const float* __restrict__ thr, const float* __restrict__ We,
    const float* __restrict__ Wr, char* __restrict__ ws) {
  _Float16* wrec16 = (_Float16*)(ws + WS_WREC);
  _Float16* we16 = (_Float16*)(ws + WS_WE);
  _Float16* wr16 = (_Float16*)(ws + WS_WR);
  float* wc = (float*)(ws + WS_WC);
  float* bc = (float*)(ws + WS_BC);
  float* dec = (float*)(ws + WS_DEC);
  float* lam = (float*)(ws + WS_LAM);
  const int tid = threadIdx.x, bid = blockIdx.x;
  if (bid == 0) {
    __shared__ float rm[64];
    if (tid < 64) {
      float s = 0.f;
      for (int m = 0; m < 64; ++m) s += W_rec[tid * 64 + m];
      rm[tid] = s * (1.f / 64.f);
    }
    __syncthreads();
    for (int idx = tid; idx < 4096; idx += 256) {
      const int j = idx & 3, l = (idx >> 2) & 63, kt = (idx >> 8) & 3, mt = idx >> 10;
      const int k_in = kt * 16 + ((l >> 4) << 2) + j, m = mt * 16 + (l & 15);
      wrec16[idx] = (_Float16)(W_rec[k_in * 64 + m] - rm[k_in]);
    }
    if (tid < 64) {
      float sw = 0.f, sb = 0.f;
      for (int i = 0; i < 64; ++i) { sw += w_in[i]; sb += b_in[i]; }
      wc[tid] = w_in[tid] - sw * (1.f / 64.f);
      bc[tid] = b_in[tid] - sb * (1.f / 64.f);
      dec[tid] = 1.f - DTC / softplus_fast(tau[tid]);
    }
    for (int i = tid; i < 512; i += 256) lam[i] = softplus_fast(thr[i]);
  } else {
    const int stride = (gridDim.x - 1) * 256;
    for (int i = (bid - 1) * 256 + tid; i < 57344 + 32768; i += stride) {
      if (i < 57344) {
        const int row = i / 112, t = i - row * 112;
        we16[i] = (t < WIN) ? (_Float16)We[row * WIN + t] : (_Float16)0.f;
      } else {
        const int j = i - 57344;
        wr16[j] = (_Float16)Wr[j];
      }
    }
  }
}

// ======================= main kernel =======================
__global__ __launch_bounds__(64, 2) void pinn_fused(
    const float* __restrict__ y, const float* __restrict__ ln_w,
    const float* __restrict__ ln_b, const float* __restrict__ Wx0,
    const float* __restrict__ bx0, const float* __restrict__ be,
    const float* __restrict__ head_W, const float* __restrict__ head_b,
    const char* __restrict__ ws, float* __restrict__ out) {
  __shared__ float ybuf[16][101];  // (c*101)%32 all distinct -> conflict-free columns

  const _Float16* wrec16 = (const _Float16*)(ws + WS_WREC);
  const _Float16* we16 = (const _Float16*)(ws + WS_WE);
  const _Float16* wr16 = (const _Float16*)(ws + WS_WR);
  const float* wcp = (const float*)(ws + WS_WC);
  const float* bcp = (const float*)(ws + WS_BC);
  const float* decp = (const float*)(ws + WS_DEC);
  const float* lamp = (const float*)(ws + WS_LAM);

  const int l = threadIdx.x;
  const int c = l & 15;  // sample (C col / B col / A row)
  const int g = l >> 4;  // lane group
  const int s0 = blockIdx.x * 16;

  // ---- stage y tile ----
  for (int i = l; i < 16 * WIN; i += 64) {
    const int s = i / WIN;
    ybuf[s][i - s * WIN] = y[s0 * WIN + i];
  }

  // ---- per-H constants as f16x2 pairs: pair i=mt*2+p covers e=4*? ----
  // element index e = mt*4 + r -> H = mt*16 + 4g + r; pair i = e>>1
  f16x2v wc2[8], bc2[8], lnw2[8], lnb2[8], dec2[8];
#pragma unroll
  for (int mt = 0; mt < 4; ++mt) {
    const int hb4 = mt * 16 + g * 4;
    const float4 wi = *(const float4*)&wcp[hb4];
    const float4 bi = *(const float4*)&bcp[hb4];
    const float4 lw = *(const float4*)&ln_w[hb4];
    const float4 lb = *(const float4*)&ln_b[hb4];
    const float4 dc = *(const float4*)&decp[hb4];
    wc2[mt * 2] = pk2(wi.x, wi.y);
    wc2[mt * 2 + 1] = pk2(wi.z, wi.w);
    bc2[mt * 2] = pk2(bi.x, bi.y);
    bc2[mt * 2 + 1] = pk2(bi.z, bi.w);
    lnw2[mt * 2] = pk2(lw.x, lw.y);
    lnw2[mt * 2 + 1] = pk2(lw.z, lw.w);
    lnb2[mt * 2] = pk2(lb.x, lb.y);
    lnb2[mt * 2 + 1] = pk2(lb.z, lb.w);
    dec2[mt * 2] = pk2(dc.x, dc.y);
    dec2[mt * 2 + 1] = pk2(dc.z, dc.w);
  }

  // ---- centered W' A-fragments ----
  f16x4 wrec[4][4];
#pragma unroll
  for (int mt = 0; mt < 4; ++mt)
#pragma unroll
    for (int kt = 0; kt < 4; ++kt)
      wrec[mt][kt] = *(const f16x4*)&wrec16[((mt * 4 + kt) * 64 + l) * 4];

  __syncthreads();  // ybuf ready

  // h state: hs2[i] f16x2 pairs; hb[kt] = concat(hs2[2kt], hs2[2kt+1])
  f16x2v hs2[8];
#pragma unroll
  for (int i = 0; i < 8; ++i) hs2[i] = pk2(0.f, 0.f);
  f16x4 hb[4];
#pragma unroll
  for (int kt = 0; kt < 4; ++kt) {
    HS u;
    u.p[0] = hs2[2 * kt];
    u.p[1] = hs2[2 * kt + 1];
    hb[kt] = u.v;
  }
  const float inv64 = 1.0f / 64.0f;

  // Pade / clamp constants (packed f16)
  const f16x2v c0p1n = pk2(0.1f, 0.1f);     // num fold: 0.1
  const f16x2v c1p5 = pk2(1.5f, 1.5f);
  const f16x2v c6 = pk2(6.f, 6.f);
  const f16x2v c15 = pk2(15.f, 15.f);
  const f16x2v cP = pk2(0.1f, 0.1f);        // drive clamp +/-0.1
  const f16x2v cM = pk2(-0.1f, -0.1f);
  const f16x2v c10 = pk2(10.f, 10.f);
  const f16x2v cm10 = pk2(-10.f, -10.f);

  // ================= Phase 1: 100-step scan =================
  float xt = ybuf[c][0];
  for (int t = 0; t < WIN; ++t) {
    const float xtn = ybuf[c][t + 1];  // col 100 in-bounds (padded), unused at t=99
    const f16x2v xtv = pk2(xt, xt);
    f32x4 acc[4];
#pragma unroll
    for (int mt = 0; mt < 4; ++mt) {
      f32x4 a = {0.f, 0.f, 0.f, 0.f};
#pragma unroll
      for (int kt = 0; kt < 4; ++kt)
        a = __builtin_amdgcn_mfma_f32_16x16x16f16(wrec[mt][kt], hb[kt], a, 0, 0, 0);
      acc[mt] = a;
    }
    // pre (f16 pairs) + variance partial via dot2 (f32 accum)
    f16x2v pre2[8];
    float q = 0.f;
#pragma unroll
    for (int mt = 0; mt < 4; ++mt)
#pragma unroll
      for (int p = 0; p < 2; ++p) {
        const int i = mt * 2 + p;
        const f16x2v d = pk2(acc[mt][2 * p], acc[mt][2 * p + 1]);
        const f16x2v tb = __builtin_elementwise_fma(xtv, wc2[i], bc2[i]);
        const f16x2v pre = d + tb;
        pre2[i] = pre;
        q = fdot2f(pre, pre, q);
      }
    q += __shfl_xor(q, 16);
    q += __shfl_xor(q, 32);
    const float rstd = rsq_fast(fmaf(q, inv64, LNEPS));
    const f16x2v rstdv = pk2(rstd, rstd);
#pragma unroll
    for (int i = 0; i < 8; ++i) {
      const f16x2v u = __builtin_elementwise_fma(pre2[i] * rstdv, lnw2[i], lnb2[i]);
      const f16x2v x2 = u * u;
      const f16x2v n1 = __builtin_elementwise_fma(x2, c0p1n, c1p5);  // 1.5 + 0.1 u^2
      const f16x2v num = u * n1;
      const f16x2v den = __builtin_elementwise_fma(x2, c6, c15);     // 15 + 6 u^2
      f16x2v tt = num * rcp2(den);                                   // ~0.1*tanh(u)
      tt = __builtin_elementwise_min(tt, cP);
      tt = __builtin_elementwise_max(tt, cM);
      f16x2v h = __builtin_elementwise_fma(hs2[i], dec2[i], tt);
      h = __builtin_elementwise_min(h, c10);
      h = __builtin_elementwise_max(h, cm10);
      hs2[i] = h;
    }
#pragma unroll
    for (int kt = 0; kt < 4; ++kt) {
      HS u;
      u.p[0] = hs2[2 * kt];
      u.p[1] = hs2[2 * kt + 1];
      hb[kt] = u.v;
    }
    xt = xtn;
  }

  // ================= Phase 2: x^T = Wx0 @ h^T + bx0 =================
  float xs[16];
  f16x4 xfr[4];
#pragma unroll
  for (int mt = 0; mt < 4; ++mt) {
    const float4 b4 = *(const float4*)&bx0[mt * 16 + 4 * g];
    f32x4 a = {b4.x, b4.y, b4.z, b4.w};
#pragma unroll
    for (int kt = 0; kt < 4; ++kt) {
      const float4 wv = *(const float4*)&Wx0[(mt * 16 + c) * HH + kt * 16 + 4 * g];
      a = __builtin_amdgcn_mfma_f32_16x16x16f16(pack4(wv.x, wv.y, wv.z, wv.w), hb[kt], a, 0, 0, 0);
    }
#pragma unroll
    for (int r = 0; r < 4; ++r) xs[mt * 4 + r] = a[r];
    xfr[mt] = pack4(a[0], a[1], a[2], a[3]);
  }

  // ---- y^T B-fragments (t >= 100 zero; We padded to 112 in ws) ----
  f16x4 yfr[7];
#pragma unroll
  for (int kt = 0; kt < 7; ++kt) {
    const int t0 = kt * 16 + 4 * g;
    if (t0 + 3 < WIN) {
      yfr[kt] = pack4(ybuf[c][t0], ybuf[c][t0 + 1], ybuf[c][t0 + 2], ybuf[c][t0 + 3]);
    } else {
      yfr[kt] = pack4(0.f, 0.f, 0.f, 0.f);
    }
  }

  // ================= Phase 3: ISTA (Jacobi) =================
  for (int k = 0; k < KITER; ++k) {
    f32x4 z[4];
#pragma unroll
    for (int mt = 0; mt < 4; ++mt) {
      const float4 be4 = *(const float4*)&be[k * AA + mt * 16 + 4 * g];
      f32x4 a = {be4.x, be4.y, be4.z, be4.w};
      const int rowe = (k * AA + mt * 16 + c) * 112;
#pragma unroll
      for (int kt = 0; kt < 7; ++kt) {
        const f16x4 wf = *(const f16x4*)&we16[rowe + kt * 16 + 4 * g];
        a = __builtin_amdgcn_mfma_f32_16x16x16f16(wf, yfr[kt], a, 0, 0, 0);
      }
      const int rowr = (k * AA + mt * 16 + c) * AA;
#pragma unroll
      for (int kt = 0; kt < 4; ++kt) {
        const f16x4 wf = *(const f16x4*)&wr16[rowr + kt * 16 + 4 * g];
        a = __builtin_amdgcn_mfma_f32_16x16x16f16(wf, xfr[kt], a, 0, 0, 0);
      }
      z[mt] = a;
    }
#pragma unroll
    for (int mt = 0; mt < 4; ++mt) {
      const float4 lm4 = *(const float4*)&lamp[k * AA + mt * 16 + 4 * g];
      float xv[4];
#pragma unroll
      for (int r = 0; r < 4; ++r) {
        const float zz = z[mt][r];
        const float v = fmaxf(fabsf(zz) - (&lm4.x)[r], 0.0f);
        xv[r] = copysignf(v, zz);
        xs[mt * 4 + r] = xv[r];
      }
      xfr[mt] = pack4(xv[0], xv[1], xv[2], xv[3]);
    }
  }

  // ================= Phase 4: outputs =================
  float* __restrict__ outp = out;               // power (B, 4)
  float* __restrict__ outx = out + NB * NAPPC;  // x (B, 64)
#pragma unroll
  for (int mt = 0; mt < 4; ++mt) {
    float4 v;
#pragma unroll
    for (int r = 0; r < 4; ++r) (&v.x)[r] = xs[mt * 4 + r];
    *(float4*)&outx[(s0 + c) * AA + mt * 16 + 4 * g] = v;
  }

  float P[4];
#pragma unroll
  for (int p = 0; p < NAPPC; ++p) {
    float acc = 0.f;
#pragma unroll
    for (int mt = 0; mt < 4; ++mt) {
      const float4 hw = *(const float4*)&head_W[p * AA + mt * 16 + 4 * g];
#pragma unroll
      for (int r = 0; r < 4; ++r) acc = fmaf(xs[mt * 4 + r], (&hw.x)[r], acc);
    }
    acc += __shfl_xor(acc, 16);
    acc += __shfl_xor(acc, 32);
    P[p] = acc + head_b[p];
  }
  if (g == 0) {
    float4 pv;
#pragma unroll
    for (int p = 0; p < 4; ++p) (&pv.x)[p] = P[p];
    *(float4*)&outp[(s0 + c) * NAPPC] = pv;
  }
}

extern "C" void kernel_launch(void* const* d_in, const int* in_sizes, int n_in,
                              void* d_out, int out_size, void* d_ws, size_t ws_size,
                              hipStream_t stream) {
  const float* y         = (const float*)d_in[0];
  const float* w_in      = (const float*)d_in[1];
  const float* b_in      = (const float*)d_in[2];
  const float* tau_param = (const float*)d_in[3];
  const float* W_rec     = (const float*)d_in[4];
  const float* ln_w      = (const float*)d_in[5];
  const float* ln_b      = (const float*)d_in[6];
  const float* Wx0       = (const float*)d_in[7];
  const float* bx0       = (const float*)d_in[8];
  const float* We        = (const float*)d_in[9];
  const float* be        = (const float*)d_in[10];
  const float* Wr        = (const float*)d_in[11];
  const float* thr       = (const float*)d_in[12];
  const float* head_W    = (const float*)d_in[13];
  const float* head_b    = (const float*)d_in[14];

  pinn_prep<<<dim3(90), dim3(256), 0, stream>>>(
      W_rec, w_in, b_in, tau_param, thr, We, Wr, (char*)d_ws);
  pinn_fused<<<dim3(NB / 16), dim3(64), 0, stream>>>(
      y, ln_w, ln_b, Wx0, bx0, be, head_W, head_b, (const char*)d_ws,
      (float*)d_out);
}